// Round 1
// 129.886 us; speedup vs baseline: 1.0197x; 1.0197x over previous
//
#include <hip/hip_runtime.h>
#include <math.h>

#define NP 196
#define PI_F 3.14159265358979323846f

// order-preserving float<->uint encoding (monotone: min of keys == key of min)
__device__ __forceinline__ unsigned fkey(float f) {
  unsigned u = __float_as_uint(f);
  return u ^ ((unsigned)((int)u >> 31) | 0x80000000u);
}
__device__ __forceinline__ float funkey(unsigned k) {
  unsigned u = (k & 0x80000000u) ? (k ^ 0x80000000u) : ~k;
  return __uint_as_float(u);
}

// ---------------------------------------------------------------------------
// K0: init mn/mx keys + precompute U (16x16 fixed 3-layer variational circuit
// as a matrix) and W2[k,p] = sum_c res_w[c]*cls_w[k, c*196+p] (residual folded
// into the classifier). Replaces the two hipMemsetAsync dispatches too.
// ---------------------------------------------------------------------------
__global__ void __launch_bounds__(256) precompute_kernel(
    const float* __restrict__ params, const float* __restrict__ res_w,
    const float* __restrict__ cls_w, float* __restrict__ U,
    float* __restrict__ W2, unsigned* __restrict__ mn,
    unsigned* __restrict__ mx) {
  const int tid = threadIdx.x;
  if (tid < NP) {
    mn[tid] = 0xFFFFFFFFu;  // uint max
    mx[tid] = 0u;           // uint min
  }
  if (tid < 16) {
    float cp[12], sp[12];
#pragma unroll
    for (int l = 0; l < 12; ++l) __sincosf(0.5f * params[l], &sp[l], &cp[l]);
    float st[16];
#pragma unroll
    for (int i = 0; i < 16; ++i) st[i] = 0.f;
    st[tid] = 1.f;  // basis vector e_j -> column j of U
#pragma unroll
    for (int l = 0; l < 3; ++l) {
#pragma unroll
      for (int q = 0; q < 4; ++q) {
        const float cq = cp[l * 4 + q], sq = sp[l * 4 + q];
        const int m = 8 >> q;
#pragma unroll
        for (int idx = 0; idx < 16; ++idx) {
          if (idx & m) continue;
          float v0 = st[idx], v1 = st[idx | m];
          st[idx] = cq * v0 - sq * v1;
          st[idx | m] = sq * v0 + cq * v1;
        }
      }
#pragma unroll
      for (int q = 0; q < 3; ++q) {
        const int mc = 8 >> q, mt = 4 >> q;
#pragma unroll
        for (int idx = 0; idx < 16; ++idx) {
          if ((idx & mc) && !(idx & mt)) {
            float t0 = st[idx];
            st[idx] = st[idx | mt];
            st[idx | mt] = t0;
          }
        }
      }
    }
#pragma unroll
    for (int i = 0; i < 16; ++i) U[i * 16 + tid] = st[i];
  }
  for (int t = tid; t < 10 * NP; t += 256) {
    int k = t / NP, p = t - k * NP;
    float s = 0.f;
#pragma unroll
    for (int c = 0; c < 4; ++c) s += res_w[c] * cls_w[k * 784 + c * NP + p];
    W2[t] = s;
  }
}

// ---------------------------------------------------------------------------
// K1: per-patch-position min/max over the batch. No atomics in the hot loop:
// thread t<392 owns one (row, col-pair) position, register-reduces over
// `imgs` images with coalesced float2 loads; one global atomic per patch/blk.
// ---------------------------------------------------------------------------
__global__ void __launch_bounds__(512) minmax_kernel(
    const float* __restrict__ x, unsigned* __restrict__ mn,
    unsigned* __restrict__ mx, int imgs, int B) {
  __shared__ unsigned skmin[392], skmax[392];
  const int t = threadIdx.x;
  const int img0 = blockIdx.x * imgs;
  if (t < 392) {
    const int r = t / 14, j = t - r * 14;
    const float* base = x + (size_t)img0 * 784 + r * 28 + 2 * j;
    float lmn = 3.4e38f, lmx = -3.4e38f;
    const int nimg = (img0 + imgs <= B) ? imgs : (B - img0);
#pragma unroll 4
    for (int m = 0; m < nimg; ++m) {
      float2 v = *(const float2*)(base + (size_t)m * 784);
      lmn = fminf(lmn, fminf(v.x, v.y));
      lmx = fmaxf(lmx, fmaxf(v.x, v.y));
    }
    skmin[t] = fkey(lmn);
    skmax[t] = fkey(lmx);
  }
  __syncthreads();
  if (t < NP) {
    const int i = t / 14, j = t - i * 14;
    const int f0 = (2 * i) * 14 + j, f1 = f0 + 14;
    unsigned kmn = skmin[f0] < skmin[f1] ? skmin[f0] : skmin[f1];
    unsigned kmx = skmax[f0] > skmax[f1] ? skmax[f0] : skmax[f1];
    atomicMin(&mn[t], kmn);
    atomicMax(&mx[t], kmx);
  }
}

// ---------------------------------------------------------------------------
// K2 (fused circuit + classifier): one image per 256-thread block.
//   Phase 1: threads 0..195 each run one patch circuit (product state +
//            16x16 U matvec + Walsh butterfly for the 4 <Z_w>), meas -> LDS
//            in the reference flat order f = p*4 + w; residual pixel -> LDS.
//   Phase 2: 256 threads do the 10-way classifier dot over LDS (incl. folded
//            residual via W2), wave shfl-reduce, log_softmax by thread 0.
// Eliminates the 25.7MB gmeas HBM round-trip and one kernel launch.
// ---------------------------------------------------------------------------
__global__ void __launch_bounds__(256) fused_kernel(
    const float* __restrict__ x, const unsigned* __restrict__ mnk,
    const unsigned* __restrict__ mxk, const float* __restrict__ U,
    const float* __restrict__ W2, const float* __restrict__ cls_w,
    const float* __restrict__ cls_b, float* __restrict__ out) {
  __shared__ float lmeas[784];   // flat f = p*4 + w (reference meas order)
  __shared__ float respix[NP];   // img[2i, 2j] for the residual
  __shared__ float partial[4][10];

  const int t = threadIdx.x;
  const int b = blockIdx.x;

  if (t < NP) {
    const int p = t;
    const int i = p / 14, j = p - i * 14;
    const float* px = x + (size_t)b * 784 + (2 * i) * 28 + 2 * j;
    const float2 r0 = *(const float2*)px;
    const float2 r1 = *(const float2*)(px + 28);

    const float mnv = funkey(mnk[p]);
    const float mxv = funkey(mxk[p]);
    const float sc = (0.5f * PI_F) / (mxv - mnv + 1e-8f);  // half-angle scale

    float cc[4], ss[4];
    __sincosf((r0.x - mnv) * sc, &ss[0], &cc[0]);
    __sincosf((r0.y - mnv) * sc, &ss[1], &cc[1]);
    __sincosf((r1.x - mnv) * sc, &ss[2], &cc[2]);
    __sincosf((r1.y - mnv) * sc, &ss[3], &cc[3]);

    // product state; index bit (8>>q) = wire q
    float st0[16];
    {
      const float A[4] = {cc[0] * cc[1], cc[0] * ss[1], ss[0] * cc[1], ss[0] * ss[1]};
      const float Bq[4] = {cc[2] * cc[3], cc[2] * ss[3], ss[2] * cc[3], ss[2] * ss[3]};
#pragma unroll
      for (int idx = 0; idx < 16; ++idx) st0[idx] = A[idx >> 2] * Bq[idx & 3];
    }

    float sq[16];
#pragma unroll
    for (int i2 = 0; i2 < 16; ++i2) {
      float f = 0.f;
#pragma unroll
      for (int jx = 0; jx < 16; ++jx) f = fmaf(U[i2 * 16 + jx], st0[jx], f);
      sq[i2] = f * f;
    }
    // Walsh butterfly: z_w = sum_i (-1)^{bit_w(i)} sq_i  (w=0 <-> bit3)
    float a[8], z3 = 0.f;
#pragma unroll
    for (int k = 0; k < 8; ++k) {
      a[k] = sq[2 * k] + sq[2 * k + 1];
      z3 += sq[2 * k] - sq[2 * k + 1];
    }
    float bb[4], z2 = 0.f;
#pragma unroll
    for (int k = 0; k < 4; ++k) {
      bb[k] = a[2 * k] + a[2 * k + 1];
      z2 += a[2 * k] - a[2 * k + 1];
    }
    const float e0 = bb[0] + bb[1], e1 = bb[2] + bb[3];
    const float z1 = (bb[0] - bb[1]) + (bb[2] - bb[3]);
    const float z0 = e0 - e1;

    lmeas[4 * p + 0] = z0;
    lmeas[4 * p + 1] = z1;
    lmeas[4 * p + 2] = z2;
    lmeas[4 * p + 3] = z3;
    respix[p] = r0.x;
  }
  __syncthreads();

  float acc[10];
#pragma unroll
  for (int k = 0; k < 10; ++k) acc[k] = 0.f;

  for (int f = t; f < 784; f += 256) {
    const float v = lmeas[f];
#pragma unroll
    for (int k = 0; k < 10; ++k) acc[k] = fmaf(v, cls_w[k * 784 + f], acc[k]);
  }
  if (t < NP) {
    const float v = respix[t];
#pragma unroll
    for (int k = 0; k < 10; ++k) acc[k] = fmaf(v, W2[k * NP + t], acc[k]);
  }

  const int lane = t & 63, wv = t >> 6;
#pragma unroll
  for (int k = 0; k < 10; ++k) {
    float v = acc[k];
#pragma unroll
    for (int off = 32; off > 0; off >>= 1) v += __shfl_down(v, off, 64);
    if (lane == 0) partial[wv][k] = v;
  }
  __syncthreads();

  if (t == 0) {
    float lg[10];
#pragma unroll
    for (int k = 0; k < 10; ++k)
      lg[k] = partial[0][k] + partial[1][k] + partial[2][k] + partial[3][k] + cls_b[k];
    float m = lg[0];
#pragma unroll
    for (int k = 1; k < 10; ++k) m = fmaxf(m, lg[k]);
    float s = 0.f;
#pragma unroll
    for (int k = 0; k < 10; ++k) s += __expf(lg[k] - m);
    const float lse = m + __logf(s);
#pragma unroll
    for (int k = 0; k < 10; ++k) out[(size_t)b * 10 + k] = lg[k] - lse;
  }
}

extern "C" void kernel_launch(void* const* d_in, const int* in_sizes, int n_in,
                              void* d_out, int out_size, void* d_ws, size_t ws_size,
                              hipStream_t stream) {
  const float* x      = (const float*)d_in[0];
  const float* params = (const float*)d_in[1];
  const float* res_w  = (const float*)d_in[2];
  const float* cls_w  = (const float*)d_in[3];
  const float* cls_b  = (const float*)d_in[4];
  float* out = (float*)d_out;
  const int B = in_sizes[0] / 784;

  // ws layout: mn[196] u32 | mx[196] u32 | U[256] f32 | W2[1960] f32
  unsigned* mn = (unsigned*)d_ws;
  unsigned* mx = mn + NP;
  float* U  = (float*)(mx + NP);
  float* W2 = U + 256;

  // K0 also initializes mn/mx (replaces two memset dispatches)
  precompute_kernel<<<1, 256, 0, stream>>>(params, res_w, cls_w, U, W2, mn, mx);

  const int imgs = 16;
  const int nblk1 = (B + imgs - 1) / imgs;
  minmax_kernel<<<nblk1, 512, 0, stream>>>(x, mn, mx, imgs, B);

  fused_kernel<<<B, 256, 0, stream>>>(x, mn, mx, U, W2, cls_w, cls_b, out);
}

// Round 2
// 127.060 us; speedup vs baseline: 1.0424x; 1.0222x over previous
//
#include <hip/hip_runtime.h>
#include <math.h>

#define NP 196
#define PI_F 3.14159265358979323846f

// order-preserving float<->uint encoding (monotone: min of keys == key of min)
__device__ __forceinline__ unsigned fkey(float f) {
  unsigned u = __float_as_uint(f);
  return u ^ ((unsigned)((int)u >> 31) | 0x80000000u);
}
__device__ __forceinline__ float funkey(unsigned k) {
  unsigned u = (k & 0x80000000u) ? (k ^ 0x80000000u) : ~k;
  return __uint_as_float(u);
}

// ---------------------------------------------------------------------------
// K0: init mn/mx keys + precompute U (16x16 fixed 3-layer variational circuit
// as a matrix) and W2[k,p] = sum_c res_w[c]*cls_w[k, c*196+p] (residual folded
// into the classifier).
// ---------------------------------------------------------------------------
__global__ void __launch_bounds__(256) precompute_kernel(
    const float* __restrict__ params, const float* __restrict__ res_w,
    const float* __restrict__ cls_w, float* __restrict__ U,
    float* __restrict__ W2, unsigned* __restrict__ mn,
    unsigned* __restrict__ mx) {
  const int tid = threadIdx.x;
  if (tid < NP) {
    mn[tid] = 0xFFFFFFFFu;  // uint max
    mx[tid] = 0u;           // uint min
  }
  if (tid < 16) {
    float cp[12], sp[12];
#pragma unroll
    for (int l = 0; l < 12; ++l) __sincosf(0.5f * params[l], &sp[l], &cp[l]);
    float st[16];
#pragma unroll
    for (int i = 0; i < 16; ++i) st[i] = 0.f;
    st[tid] = 1.f;  // basis vector e_j -> column j of U
#pragma unroll
    for (int l = 0; l < 3; ++l) {
#pragma unroll
      for (int q = 0; q < 4; ++q) {
        const float cq = cp[l * 4 + q], sq = sp[l * 4 + q];
        const int m = 8 >> q;
#pragma unroll
        for (int idx = 0; idx < 16; ++idx) {
          if (idx & m) continue;
          float v0 = st[idx], v1 = st[idx | m];
          st[idx] = cq * v0 - sq * v1;
          st[idx | m] = sq * v0 + cq * v1;
        }
      }
#pragma unroll
      for (int q = 0; q < 3; ++q) {
        const int mc = 8 >> q, mt = 4 >> q;
#pragma unroll
        for (int idx = 0; idx < 16; ++idx) {
          if ((idx & mc) && !(idx & mt)) {
            float t0 = st[idx];
            st[idx] = st[idx | mt];
            st[idx | mt] = t0;
          }
        }
      }
    }
#pragma unroll
    for (int i = 0; i < 16; ++i) U[i * 16 + tid] = st[i];
  }
  for (int t = tid; t < 10 * NP; t += 256) {
    int k = t / NP, p = t - k * NP;
    float s = 0.f;
#pragma unroll
    for (int c = 0; c < 4; ++c) s += res_w[c] * cls_w[k * 784 + c * NP + p];
    W2[t] = s;
  }
}

// ---------------------------------------------------------------------------
// K1: per-patch-position min/max over the batch. Two independent accumulator
// pairs break the 4-cycle fmin/fmax dependency chain; one atomic per
// patch/block at the end.
// ---------------------------------------------------------------------------
__global__ void __launch_bounds__(512) minmax_kernel(
    const float* __restrict__ x, unsigned* __restrict__ mn,
    unsigned* __restrict__ mx, int imgs, int B) {
  __shared__ unsigned skmin[392], skmax[392];
  const int t = threadIdx.x;
  const int img0 = blockIdx.x * imgs;
  if (t < 392) {
    const int r = t / 14, j = t - r * 14;
    const float* base = x + (size_t)img0 * 784 + r * 28 + 2 * j;
    const int nimg = (img0 + imgs <= B) ? imgs : (B - img0);
    float lmn0 = 3.4e38f, lmn1 = 3.4e38f;
    float lmx0 = -3.4e38f, lmx1 = -3.4e38f;
    int m = 0;
#pragma unroll 4
    for (; m + 1 < nimg; m += 2) {
      float2 v0 = *(const float2*)(base + (size_t)m * 784);
      float2 v1 = *(const float2*)(base + (size_t)(m + 1) * 784);
      lmn0 = fminf(lmn0, fminf(v0.x, v0.y));
      lmx0 = fmaxf(lmx0, fmaxf(v0.x, v0.y));
      lmn1 = fminf(lmn1, fminf(v1.x, v1.y));
      lmx1 = fmaxf(lmx1, fmaxf(v1.x, v1.y));
    }
    if (m < nimg) {
      float2 v0 = *(const float2*)(base + (size_t)m * 784);
      lmn0 = fminf(lmn0, fminf(v0.x, v0.y));
      lmx0 = fmaxf(lmx0, fmaxf(v0.x, v0.y));
    }
    skmin[t] = fkey(fminf(lmn0, lmn1));
    skmax[t] = fkey(fmaxf(lmx0, lmx1));
  }
  __syncthreads();
  if (t < NP) {
    const int i = t / 14, j = t - i * 14;
    const int f0 = (2 * i) * 14 + j, f1 = f0 + 14;
    unsigned kmn = skmin[f0] < skmin[f1] ? skmin[f0] : skmin[f1];
    unsigned kmx = skmax[f0] > skmax[f1] ? skmax[f0] : skmax[f1];
    atomicMin(&mn[t], kmn);
    atomicMax(&mx[t], kmx);
  }
}

// ---------------------------------------------------------------------------
// K2 (fused circuit + classifier, register-direct): one image per 256-thread
// block. Threads 0..195 each run one patch circuit and immediately fold their
// four <Z_w> values + residual pixel into 10 per-thread partial logits
// (cls_w[k*784+4p..+3] is one aligned float4). No meas LDS staging, no
// strided re-read phase, one barrier total before the cross-wave reduce.
// ---------------------------------------------------------------------------
__global__ void __launch_bounds__(256) fused_kernel(
    const float* __restrict__ x, const unsigned* __restrict__ mnk,
    const unsigned* __restrict__ mxk, const float* __restrict__ U,
    const float* __restrict__ W2, const float* __restrict__ cls_w,
    const float* __restrict__ cls_b, float* __restrict__ out) {
  __shared__ float partial[4][10];

  const int t = threadIdx.x;
  const int b = blockIdx.x;

  float acc[10];
#pragma unroll
  for (int k = 0; k < 10; ++k) acc[k] = 0.f;

  if (t < NP) {
    const int p = t;
    const int i = p / 14, j = p - i * 14;
    const float* px = x + (size_t)b * 784 + (2 * i) * 28 + 2 * j;
    const float2 r0 = *(const float2*)px;
    const float2 r1 = *(const float2*)(px + 28);

    const float mnv = funkey(mnk[p]);
    const float mxv = funkey(mxk[p]);
    const float sc = (0.5f * PI_F) / (mxv - mnv + 1e-8f);  // half-angle scale

    float cc[4], ss[4];
    __sincosf((r0.x - mnv) * sc, &ss[0], &cc[0]);
    __sincosf((r0.y - mnv) * sc, &ss[1], &cc[1]);
    __sincosf((r1.x - mnv) * sc, &ss[2], &cc[2]);
    __sincosf((r1.y - mnv) * sc, &ss[3], &cc[3]);

    // product state; index bit (8>>q) = wire q
    float st0[16];
    {
      const float A[4] = {cc[0] * cc[1], cc[0] * ss[1], ss[0] * cc[1], ss[0] * ss[1]};
      const float Bq[4] = {cc[2] * cc[3], cc[2] * ss[3], ss[2] * cc[3], ss[2] * ss[3]};
#pragma unroll
      for (int idx = 0; idx < 16; ++idx) st0[idx] = A[idx >> 2] * Bq[idx & 3];
    }

    // matvec fused with first Walsh stage (pairs) -> a8[8], z3
    float a8[8], z3 = 0.f;
#pragma unroll
    for (int k = 0; k < 8; ++k) {
      float f0 = 0.f, f1 = 0.f;
#pragma unroll
      for (int jx = 0; jx < 16; ++jx) {
        f0 = fmaf(U[(2 * k) * 16 + jx], st0[jx], f0);
        f1 = fmaf(U[(2 * k + 1) * 16 + jx], st0[jx], f1);
      }
      const float s0 = f0 * f0, s1 = f1 * f1;
      a8[k] = s0 + s1;
      z3 += s0 - s1;
    }
    float bb[4], z2 = 0.f;
#pragma unroll
    for (int k = 0; k < 4; ++k) {
      bb[k] = a8[2 * k] + a8[2 * k + 1];
      z2 += a8[2 * k] - a8[2 * k + 1];
    }
    const float e0 = bb[0] + bb[1], e1 = bb[2] + bb[3];
    const float z1 = (bb[0] - bb[1]) + (bb[2] - bb[3]);
    const float z0 = e0 - e1;
    const float v = r0.x;  // residual pixel img[2i,2j]

    // classifier: meas flat f = 4p+w -> cls_w[k*784+4p+w] is one float4
#pragma unroll
    for (int k = 0; k < 10; ++k) {
      const float4 w4 = *(const float4*)(cls_w + k * 784 + 4 * p);
      float a = z0 * w4.x;
      a = fmaf(z1, w4.y, a);
      a = fmaf(z2, w4.z, a);
      a = fmaf(z3, w4.w, a);
      acc[k] = fmaf(v, W2[k * NP + p], a);
    }
  }

  const int lane = t & 63, wv = t >> 6;
#pragma unroll
  for (int k = 0; k < 10; ++k) {
    float a = acc[k];
#pragma unroll
    for (int off = 32; off > 0; off >>= 1) a += __shfl_down(a, off, 64);
    if (lane == 0) partial[wv][k] = a;
  }
  __syncthreads();

  if (t == 0) {
    float lg[10];
#pragma unroll
    for (int k = 0; k < 10; ++k)
      lg[k] = partial[0][k] + partial[1][k] + partial[2][k] + partial[3][k] + cls_b[k];
    float m = lg[0];
#pragma unroll
    for (int k = 1; k < 10; ++k) m = fmaxf(m, lg[k]);
    float s = 0.f;
#pragma unroll
    for (int k = 0; k < 10; ++k) s += __expf(lg[k] - m);
    const float lse = m + __logf(s);
#pragma unroll
    for (int k = 0; k < 10; ++k) out[(size_t)b * 10 + k] = lg[k] - lse;
  }
}

extern "C" void kernel_launch(void* const* d_in, const int* in_sizes, int n_in,
                              void* d_out, int out_size, void* d_ws, size_t ws_size,
                              hipStream_t stream) {
  const float* x      = (const float*)d_in[0];
  const float* params = (const float*)d_in[1];
  const float* res_w  = (const float*)d_in[2];
  const float* cls_w  = (const float*)d_in[3];
  const float* cls_b  = (const float*)d_in[4];
  float* out = (float*)d_out;
  const int B = in_sizes[0] / 784;

  // ws layout: mn[196] u32 | mx[196] u32 | U[256] f32 | W2[1960] f32
  unsigned* mn = (unsigned*)d_ws;
  unsigned* mx = mn + NP;
  float* U  = (float*)(mx + NP);
  float* W2 = U + 256;

  // K0 also initializes mn/mx (replaces memset dispatches)
  precompute_kernel<<<1, 256, 0, stream>>>(params, res_w, cls_w, U, W2, mn, mx);

  const int imgs = 16;
  const int nblk1 = (B + imgs - 1) / imgs;
  minmax_kernel<<<nblk1, 512, 0, stream>>>(x, mn, mx, imgs, B);

  fused_kernel<<<B, 256, 0, stream>>>(x, mn, mx, U, W2, cls_w, cls_b, out);
}

// Round 3
// 123.929 us; speedup vs baseline: 1.0687x; 1.0253x over previous
//
#include <hip/hip_runtime.h>
#include <math.h>

#define NP 196
#define PI_F 3.14159265358979323846f

// order-preserving float<->uint encoding (monotone: min of keys == key of min)
__device__ __forceinline__ unsigned fkey(float f) {
  unsigned u = __float_as_uint(f);
  return u ^ ((unsigned)((int)u >> 31) | 0x80000000u);
}
__device__ __forceinline__ float funkey(unsigned k) {
  unsigned u = (k & 0x80000000u) ? (k ^ 0x80000000u) : ~k;
  return __uint_as_float(u);
}

// ---------------------------------------------------------------------------
// K0: init mn/mx keys + precompute U (16x16 fixed 3-layer variational circuit
// as a matrix) and W2[k,p] = sum_c res_w[c]*cls_w[k, c*196+p] (residual folded
// into the classifier).
// ---------------------------------------------------------------------------
__global__ void __launch_bounds__(256) precompute_kernel(
    const float* __restrict__ params, const float* __restrict__ res_w,
    const float* __restrict__ cls_w, float* __restrict__ U,
    float* __restrict__ W2, unsigned* __restrict__ mn,
    unsigned* __restrict__ mx) {
  const int tid = threadIdx.x;
  if (tid < NP) {
    mn[tid] = 0xFFFFFFFFu;  // uint max
    mx[tid] = 0u;           // uint min
  }
  if (tid < 16) {
    float cp[12], sp[12];
#pragma unroll
    for (int l = 0; l < 12; ++l) __sincosf(0.5f * params[l], &sp[l], &cp[l]);
    float st[16];
#pragma unroll
    for (int i = 0; i < 16; ++i) st[i] = 0.f;
    st[tid] = 1.f;  // basis vector e_j -> column j of U
#pragma unroll
    for (int l = 0; l < 3; ++l) {
#pragma unroll
      for (int q = 0; q < 4; ++q) {
        const float cq = cp[l * 4 + q], sq = sp[l * 4 + q];
        const int m = 8 >> q;
#pragma unroll
        for (int idx = 0; idx < 16; ++idx) {
          if (idx & m) continue;
          float v0 = st[idx], v1 = st[idx | m];
          st[idx] = cq * v0 - sq * v1;
          st[idx | m] = sq * v0 + cq * v1;
        }
      }
#pragma unroll
      for (int q = 0; q < 3; ++q) {
        const int mc = 8 >> q, mt = 4 >> q;
#pragma unroll
        for (int idx = 0; idx < 16; ++idx) {
          if ((idx & mc) && !(idx & mt)) {
            float t0 = st[idx];
            st[idx] = st[idx | mt];
            st[idx | mt] = t0;
          }
        }
      }
    }
#pragma unroll
    for (int i = 0; i < 16; ++i) U[i * 16 + tid] = st[i];
  }
  for (int t = tid; t < 10 * NP; t += 256) {
    int k = t / NP, p = t - k * NP;
    float s = 0.f;
#pragma unroll
    for (int c = 0; c < 4; ++c) s += res_w[c] * cls_w[k * 784 + c * NP + p];
    W2[t] = s;
  }
}

// ---------------------------------------------------------------------------
// K1: per-patch-position min/max over the batch. Two independent accumulator
// pairs break the 4-cycle fmin/fmax dependency chain; one atomic per
// patch/block at the end.
// ---------------------------------------------------------------------------
__global__ void __launch_bounds__(512) minmax_kernel(
    const float* __restrict__ x, unsigned* __restrict__ mn,
    unsigned* __restrict__ mx, int imgs, int B) {
  __shared__ unsigned skmin[392], skmax[392];
  const int t = threadIdx.x;
  const int img0 = blockIdx.x * imgs;
  if (t < 392) {
    const int r = t / 14, j = t - r * 14;
    const float* base = x + (size_t)img0 * 784 + r * 28 + 2 * j;
    const int nimg = (img0 + imgs <= B) ? imgs : (B - img0);
    float lmn0 = 3.4e38f, lmn1 = 3.4e38f;
    float lmx0 = -3.4e38f, lmx1 = -3.4e38f;
    int m = 0;
#pragma unroll 4
    for (; m + 1 < nimg; m += 2) {
      float2 v0 = *(const float2*)(base + (size_t)m * 784);
      float2 v1 = *(const float2*)(base + (size_t)(m + 1) * 784);
      lmn0 = fminf(lmn0, fminf(v0.x, v0.y));
      lmx0 = fmaxf(lmx0, fmaxf(v0.x, v0.y));
      lmn1 = fminf(lmn1, fminf(v1.x, v1.y));
      lmx1 = fmaxf(lmx1, fmaxf(v1.x, v1.y));
    }
    if (m < nimg) {
      float2 v0 = *(const float2*)(base + (size_t)m * 784);
      lmn0 = fminf(lmn0, fminf(v0.x, v0.y));
      lmx0 = fmaxf(lmx0, fmaxf(v0.x, v0.y));
    }
    skmin[t] = fkey(fminf(lmn0, lmn1));
    skmax[t] = fkey(fmaxf(lmx0, lmx1));
  }
  __syncthreads();
  if (t < NP) {
    const int i = t / 14, j = t - i * 14;
    const int f0 = (2 * i) * 14 + j, f1 = f0 + 14;
    unsigned kmn = skmin[f0] < skmin[f1] ? skmin[f0] : skmin[f1];
    unsigned kmx = skmax[f0] > skmax[f1] ? skmax[f0] : skmax[f1];
    atomicMin(&mn[t], kmn);
    atomicMax(&mx[t], kmx);
  }
}

// ---------------------------------------------------------------------------
// K2 (fused circuit + classifier, one WAVE per image): block of 256 = 4 waves
// = 4 images. Lane l runs patches p = it*64+l (it=0..3; iteration 3 has 4
// active lanes — same 196/256 lane-slot utilization as before). Each lane
// folds its patches' four <Z_w> + residual pixel into acc[10]; then ONE
// 64-lane shfl reduce per image (was 4), no LDS, no __syncthreads, and the
// softmax epilogue runs on 4 lane-0s in parallel.
// ---------------------------------------------------------------------------
__global__ void __launch_bounds__(256) fused_kernel(
    const float* __restrict__ x, const unsigned* __restrict__ mnk,
    const unsigned* __restrict__ mxk, const float* __restrict__ U,
    const float* __restrict__ W2, const float* __restrict__ cls_w,
    const float* __restrict__ cls_b, float* __restrict__ out, int B) {
  const int lane = threadIdx.x & 63;
  const int wv = threadIdx.x >> 6;
  const int b = blockIdx.x * 4 + wv;
  if (b >= B) return;  // wave-uniform

  const float* ximg = x + (size_t)b * 784;

  float acc[10];
#pragma unroll
  for (int k = 0; k < 10; ++k) acc[k] = 0.f;

#pragma unroll 1
  for (int it = 0; it < 4; ++it) {
    const int p = it * 64 + lane;
    if (p < NP) {
      const int i = p / 14, j = p - i * 14;
      const float* px = ximg + (2 * i) * 28 + 2 * j;
      const float2 r0 = *(const float2*)px;
      const float2 r1 = *(const float2*)(px + 28);

      const float mnv = funkey(mnk[p]);
      const float mxv = funkey(mxk[p]);
      const float sc = (0.5f * PI_F) / (mxv - mnv + 1e-8f);  // half-angle scale

      float cc[4], ss[4];
      __sincosf((r0.x - mnv) * sc, &ss[0], &cc[0]);
      __sincosf((r0.y - mnv) * sc, &ss[1], &cc[1]);
      __sincosf((r1.x - mnv) * sc, &ss[2], &cc[2]);
      __sincosf((r1.y - mnv) * sc, &ss[3], &cc[3]);

      // product state; index bit (8>>q) = wire q
      float st0[16];
      {
        const float A[4] = {cc[0] * cc[1], cc[0] * ss[1], ss[0] * cc[1], ss[0] * ss[1]};
        const float Bq[4] = {cc[2] * cc[3], cc[2] * ss[3], ss[2] * cc[3], ss[2] * ss[3]};
#pragma unroll
        for (int idx = 0; idx < 16; ++idx) st0[idx] = A[idx >> 2] * Bq[idx & 3];
      }

      // matvec fused with first Walsh stage (pairs) -> a8[8], z3
      float a8[8], z3 = 0.f;
#pragma unroll
      for (int k = 0; k < 8; ++k) {
        float f0 = 0.f, f1 = 0.f;
#pragma unroll
        for (int jx = 0; jx < 16; ++jx) {
          f0 = fmaf(U[(2 * k) * 16 + jx], st0[jx], f0);
          f1 = fmaf(U[(2 * k + 1) * 16 + jx], st0[jx], f1);
        }
        const float s0 = f0 * f0, s1 = f1 * f1;
        a8[k] = s0 + s1;
        z3 += s0 - s1;
      }
      float bb[4], z2 = 0.f;
#pragma unroll
      for (int k = 0; k < 4; ++k) {
        bb[k] = a8[2 * k] + a8[2 * k + 1];
        z2 += a8[2 * k] - a8[2 * k + 1];
      }
      const float e0 = bb[0] + bb[1], e1 = bb[2] + bb[3];
      const float z1 = (bb[0] - bb[1]) + (bb[2] - bb[3]);
      const float z0 = e0 - e1;
      const float v = r0.x;  // residual pixel img[2i,2j]

      // classifier: meas flat f = 4p+w -> cls_w[k*784+4p+w] is one float4
#pragma unroll
      for (int k = 0; k < 10; ++k) {
        const float4 w4 = *(const float4*)(cls_w + k * 784 + 4 * p);
        float a = z0 * w4.x;
        a = fmaf(z1, w4.y, a);
        a = fmaf(z2, w4.z, a);
        a = fmaf(z3, w4.w, a);
        acc[k] += fmaf(v, W2[k * NP + p], a);
      }
    }
  }

  // single 64-lane reduce per image
#pragma unroll
  for (int k = 0; k < 10; ++k) {
    float a = acc[k];
#pragma unroll
    for (int off = 32; off > 0; off >>= 1) a += __shfl_down(a, off, 64);
    acc[k] = a;
  }

  if (lane == 0) {
    float lg[10];
#pragma unroll
    for (int k = 0; k < 10; ++k) lg[k] = acc[k] + cls_b[k];
    float m = lg[0];
#pragma unroll
    for (int k = 1; k < 10; ++k) m = fmaxf(m, lg[k]);
    float s = 0.f;
#pragma unroll
    for (int k = 0; k < 10; ++k) s += __expf(lg[k] - m);
    const float lse = m + __logf(s);
#pragma unroll
    for (int k = 0; k < 10; ++k) out[(size_t)b * 10 + k] = lg[k] - lse;
  }
}

extern "C" void kernel_launch(void* const* d_in, const int* in_sizes, int n_in,
                              void* d_out, int out_size, void* d_ws, size_t ws_size,
                              hipStream_t stream) {
  const float* x      = (const float*)d_in[0];
  const float* params = (const float*)d_in[1];
  const float* res_w  = (const float*)d_in[2];
  const float* cls_w  = (const float*)d_in[3];
  const float* cls_b  = (const float*)d_in[4];
  float* out = (float*)d_out;
  const int B = in_sizes[0] / 784;

  // ws layout: mn[196] u32 | mx[196] u32 | U[256] f32 | W2[1960] f32
  unsigned* mn = (unsigned*)d_ws;
  unsigned* mx = mn + NP;
  float* U  = (float*)(mx + NP);
  float* W2 = U + 256;

  // K0 also initializes mn/mx (replaces memset dispatches)
  precompute_kernel<<<1, 256, 0, stream>>>(params, res_w, cls_w, U, W2, mn, mx);

  const int imgs = 16;
  const int nblk1 = (B + imgs - 1) / imgs;
  minmax_kernel<<<nblk1, 512, 0, stream>>>(x, mn, mx, imgs, B);

  const int nblk2 = (B + 3) / 4;
  fused_kernel<<<nblk2, 256, 0, stream>>>(x, mn, mx, U, W2, cls_w, cls_b, out, B);
}

// Round 5
// 116.891 us; speedup vs baseline: 1.1331x; 1.0602x over previous
//
#include <hip/hip_runtime.h>
#include <math.h>

#define NP 196
#define PI_F 3.14159265358979323846f

// order-preserving float<->uint encoding (monotone: min of keys == key of min)
__device__ __forceinline__ unsigned fkey(float f) {
  unsigned u = __float_as_uint(f);
  return u ^ ((unsigned)((int)u >> 31) | 0x80000000u);
}
__device__ __forceinline__ float funkey(unsigned k) {
  unsigned u = (k & 0x80000000u) ? (k ^ 0x80000000u) : ~k;
  return __uint_as_float(u);
}

// ---------------------------------------------------------------------------
// K0: init mn/mx keys + precompute U (16x16 fixed 3-layer variational circuit
// as a matrix) and W2[k,p] = sum_c res_w[c]*cls_w[k, c*196+p] (residual folded
// into the classifier).
// ---------------------------------------------------------------------------
__global__ void __launch_bounds__(256) precompute_kernel(
    const float* __restrict__ params, const float* __restrict__ res_w,
    const float* __restrict__ cls_w, float* __restrict__ U,
    float* __restrict__ W2, unsigned* __restrict__ mn,
    unsigned* __restrict__ mx) {
  const int tid = threadIdx.x;
  if (tid < NP) {
    mn[tid] = 0xFFFFFFFFu;  // uint max
    mx[tid] = 0u;           // uint min
  }
  if (tid < 16) {
    float cp[12], sp[12];
#pragma unroll
    for (int l = 0; l < 12; ++l) __sincosf(0.5f * params[l], &sp[l], &cp[l]);
    float st[16];
#pragma unroll
    for (int i = 0; i < 16; ++i) st[i] = 0.f;
    st[tid] = 1.f;  // basis vector e_j -> column j of U
#pragma unroll
    for (int l = 0; l < 3; ++l) {
#pragma unroll
      for (int q = 0; q < 4; ++q) {
        const float cq = cp[l * 4 + q], sq = sp[l * 4 + q];
        const int m = 8 >> q;
#pragma unroll
        for (int idx = 0; idx < 16; ++idx) {
          if (idx & m) continue;
          float v0 = st[idx], v1 = st[idx | m];
          st[idx] = cq * v0 - sq * v1;
          st[idx | m] = sq * v0 + cq * v1;
        }
      }
#pragma unroll
      for (int q = 0; q < 3; ++q) {
        const int mc = 8 >> q, mt = 4 >> q;
#pragma unroll
        for (int idx = 0; idx < 16; ++idx) {
          if ((idx & mc) && !(idx & mt)) {
            float t0 = st[idx];
            st[idx] = st[idx | mt];
            st[idx | mt] = t0;
          }
        }
      }
    }
#pragma unroll
    for (int i = 0; i < 16; ++i) U[i * 16 + tid] = st[i];
  }
  for (int t = tid; t < 10 * NP; t += 256) {
    int k = t / NP, p = t - k * NP;
    float s = 0.f;
#pragma unroll
    for (int c = 0; c < 4; ++c) s += res_w[c] * cls_w[k * 784 + c * NP + p];
    W2[t] = s;
  }
}

// ---------------------------------------------------------------------------
// K1: per-patch-position min/max over the batch. Two independent accumulator
// pairs break the fmin/fmax dependency chain; imgs=32 halves block count and
// per-address atomic contention vs imgs=16 (in-flight depth still >> BW*lat).
// ---------------------------------------------------------------------------
__global__ void __launch_bounds__(512) minmax_kernel(
    const float* __restrict__ x, unsigned* __restrict__ mn,
    unsigned* __restrict__ mx, int imgs, int B) {
  __shared__ unsigned skmin[392], skmax[392];
  const int t = threadIdx.x;
  const int img0 = blockIdx.x * imgs;
  if (t < 392) {
    const int r = t / 14, j = t - r * 14;
    const float* base = x + (size_t)img0 * 784 + r * 28 + 2 * j;
    const int nimg = (img0 + imgs <= B) ? imgs : (B - img0);
    float lmn0 = 3.4e38f, lmn1 = 3.4e38f;
    float lmx0 = -3.4e38f, lmx1 = -3.4e38f;
    int m = 0;
#pragma unroll 4
    for (; m + 1 < nimg; m += 2) {
      float2 v0 = *(const float2*)(base + (size_t)m * 784);
      float2 v1 = *(const float2*)(base + (size_t)(m + 1) * 784);
      lmn0 = fminf(lmn0, fminf(v0.x, v0.y));
      lmx0 = fmaxf(lmx0, fmaxf(v0.x, v0.y));
      lmn1 = fminf(lmn1, fminf(v1.x, v1.y));
      lmx1 = fmaxf(lmx1, fmaxf(v1.x, v1.y));
    }
    if (m < nimg) {
      float2 v0 = *(const float2*)(base + (size_t)m * 784);
      lmn0 = fminf(lmn0, fminf(v0.x, v0.y));
      lmx0 = fmaxf(lmx0, fmaxf(v0.x, v0.y));
    }
    skmin[t] = fkey(fminf(lmn0, lmn1));
    skmax[t] = fkey(fmaxf(lmx0, lmx1));
  }
  __syncthreads();
  if (t < NP) {
    const int i = t / 14, j = t - i * 14;
    const int f0 = (2 * i) * 14 + j, f1 = f0 + 14;
    unsigned kmn = skmin[f0] < skmin[f1] ? skmin[f0] : skmin[f1];
    unsigned kmx = skmax[f0] > skmax[f1] ? skmax[f0] : skmax[f1];
    atomicMin(&mn[t], kmn);
    atomicMax(&mx[t], kmx);
  }
}

// ---------------------------------------------------------------------------
// K2 (fused circuit + classifier, one WAVE per image): block of 256 = 4 waves
// = 4 images. Lane l runs patches p = it*64+l. sin/cos via raw v_sin/v_cos
// (revolutions semantics): half-angle/(2pi) = 0.25*(v-mn)/(range+1e-8), in
// [0,0.25] -> no range reduction needed (exact algebra vs reference).
// ---------------------------------------------------------------------------
__global__ void __launch_bounds__(256) fused_kernel(
    const float* __restrict__ x, const unsigned* __restrict__ mnk,
    const unsigned* __restrict__ mxk, const float* __restrict__ U,
    const float* __restrict__ W2, const float* __restrict__ cls_w,
    const float* __restrict__ cls_b, float* __restrict__ out, int B) {
  const int lane = threadIdx.x & 63;
  const int wv = threadIdx.x >> 6;
  const int b = blockIdx.x * 4 + wv;
  if (b >= B) return;  // wave-uniform

  const float* ximg = x + (size_t)b * 784;

  float acc[10];
#pragma unroll
  for (int k = 0; k < 10; ++k) acc[k] = 0.f;

#pragma unroll 1
  for (int it = 0; it < 4; ++it) {
    const int p = it * 64 + lane;
    if (p < NP) {
      const int i = p / 14, j = p - i * 14;
      const float* px = ximg + (2 * i) * 28 + 2 * j;
      const float2 r0 = *(const float2*)px;
      const float2 r1 = *(const float2*)(px + 28);

      const float mnv = funkey(mnk[p]);
      const float mxv = funkey(mxk[p]);
      // half-angle in revolutions: 0.25*(v-mn)/(range+1e-8) in [0,0.25]
      const float sc = 0.25f / (mxv - mnv + 1e-8f);

      float cc[4], ss[4];
      {
        const float a0 = (r0.x - mnv) * sc;
        const float a1 = (r0.y - mnv) * sc;
        const float a2 = (r1.x - mnv) * sc;
        const float a3 = (r1.y - mnv) * sc;
        ss[0] = __builtin_amdgcn_sinf(a0); cc[0] = __builtin_amdgcn_cosf(a0);
        ss[1] = __builtin_amdgcn_sinf(a1); cc[1] = __builtin_amdgcn_cosf(a1);
        ss[2] = __builtin_amdgcn_sinf(a2); cc[2] = __builtin_amdgcn_cosf(a2);
        ss[3] = __builtin_amdgcn_sinf(a3); cc[3] = __builtin_amdgcn_cosf(a3);
      }

      // product state; index bit (8>>q) = wire q
      float st0[16];
      {
        const float A[4] = {cc[0] * cc[1], cc[0] * ss[1], ss[0] * cc[1], ss[0] * ss[1]};
        const float Bq[4] = {cc[2] * cc[3], cc[2] * ss[3], ss[2] * cc[3], ss[2] * ss[3]};
#pragma unroll
        for (int idx = 0; idx < 16; ++idx) st0[idx] = A[idx >> 2] * Bq[idx & 3];
      }

      // matvec fused with first Walsh stage (pairs) -> a8[8], z3
      float a8[8], z3 = 0.f;
#pragma unroll
      for (int k = 0; k < 8; ++k) {
        float f0 = 0.f, f1 = 0.f;
#pragma unroll
        for (int jx = 0; jx < 16; ++jx) {
          f0 = fmaf(U[(2 * k) * 16 + jx], st0[jx], f0);
          f1 = fmaf(U[(2 * k + 1) * 16 + jx], st0[jx], f1);
        }
        const float s0 = f0 * f0, s1 = f1 * f1;
        a8[k] = s0 + s1;
        z3 += s0 - s1;
      }
      float bb[4], z2 = 0.f;
#pragma unroll
      for (int k = 0; k < 4; ++k) {
        bb[k] = a8[2 * k] + a8[2 * k + 1];
        z2 += a8[2 * k] - a8[2 * k + 1];
      }
      const float e0 = bb[0] + bb[1], e1 = bb[2] + bb[3];
      const float z1 = (bb[0] - bb[1]) + (bb[2] - bb[3]);
      const float z0 = e0 - e1;
      const float v = r0.x;  // residual pixel img[2i,2j]

      // classifier: meas flat f = 4p+w -> cls_w[k*784+4p+w] is one float4
#pragma unroll
      for (int k = 0; k < 10; ++k) {
        const float4 w4 = *(const float4*)(cls_w + k * 784 + 4 * p);
        float a = z0 * w4.x;
        a = fmaf(z1, w4.y, a);
        a = fmaf(z2, w4.z, a);
        a = fmaf(z3, w4.w, a);
        acc[k] += fmaf(v, W2[k * NP + p], a);
      }
    }
  }

  // single 64-lane reduce per image
#pragma unroll
  for (int k = 0; k < 10; ++k) {
    float a = acc[k];
#pragma unroll
    for (int off = 32; off > 0; off >>= 1) a += __shfl_down(a, off, 64);
    acc[k] = a;
  }

  if (lane == 0) {
    float lg[10];
#pragma unroll
    for (int k = 0; k < 10; ++k) lg[k] = acc[k] + cls_b[k];
    float m = lg[0];
#pragma unroll
    for (int k = 1; k < 10; ++k) m = fmaxf(m, lg[k]);
    float s = 0.f;
#pragma unroll
    for (int k = 0; k < 10; ++k) s += __expf(lg[k] - m);
    const float lse = m + __logf(s);
#pragma unroll
    for (int k = 0; k < 10; ++k) out[(size_t)b * 10 + k] = lg[k] - lse;
  }
}

extern "C" void kernel_launch(void* const* d_in, const int* in_sizes, int n_in,
                              void* d_out, int out_size, void* d_ws, size_t ws_size,
                              hipStream_t stream) {
  const float* x      = (const float*)d_in[0];
  const float* params = (const float*)d_in[1];
  const float* res_w  = (const float*)d_in[2];
  const float* cls_w  = (const float*)d_in[3];
  const float* cls_b  = (const float*)d_in[4];
  float* out = (float*)d_out;
  const int B = in_sizes[0] / 784;

  // ws layout: mn[196] u32 | mx[196] u32 | U[256] f32 | W2[1960] f32
  unsigned* mn = (unsigned*)d_ws;
  unsigned* mx = mn + NP;
  float* U  = (float*)(mx + NP);
  float* W2 = U + 256;

  precompute_kernel<<<1, 256, 0, stream>>>(params, res_w, cls_w, U, W2, mn, mx);

  const int imgs = 32;
  const int nblk1 = (B + imgs - 1) / imgs;
  minmax_kernel<<<nblk1, 512, 0, stream>>>(x, mn, mx, imgs, B);

  const int nblk2 = (B + 3) / 4;
  fused_kernel<<<nblk2, 256, 0, stream>>>(x, mn, mx, U, W2, cls_w, cls_b, out, B);
}

// Round 6
// 115.885 us; speedup vs baseline: 1.1429x; 1.0087x over previous
//
#include <hip/hip_runtime.h>
#include <math.h>

#define NP 196
#define PI_F 3.14159265358979323846f

// order-preserving float<->uint encoding (monotone: min of keys == key of min)
__device__ __forceinline__ unsigned fkey(float f) {
  unsigned u = __float_as_uint(f);
  return u ^ ((unsigned)((int)u >> 31) | 0x80000000u);
}
__device__ __forceinline__ float funkey(unsigned k) {
  unsigned u = (k & 0x80000000u) ? (k ^ 0x80000000u) : ~k;
  return __uint_as_float(u);
}

// ---------------------------------------------------------------------------
// K0: init mn/mx keys + precompute U (16x16 fixed 3-layer variational circuit
// as a matrix) and W2[k,p] = sum_c res_w[c]*cls_w[k, c*196+p] (residual folded
// into the classifier).
// ---------------------------------------------------------------------------
__global__ void __launch_bounds__(256) precompute_kernel(
    const float* __restrict__ params, const float* __restrict__ res_w,
    const float* __restrict__ cls_w, float* __restrict__ U,
    float* __restrict__ W2, unsigned* __restrict__ mn,
    unsigned* __restrict__ mx) {
  const int tid = threadIdx.x;
  if (tid < NP) {
    mn[tid] = 0xFFFFFFFFu;  // uint max
    mx[tid] = 0u;           // uint min
  }
  if (tid < 16) {
    float cp[12], sp[12];
#pragma unroll
    for (int l = 0; l < 12; ++l) __sincosf(0.5f * params[l], &sp[l], &cp[l]);
    float st[16];
#pragma unroll
    for (int i = 0; i < 16; ++i) st[i] = 0.f;
    st[tid] = 1.f;  // basis vector e_j -> column j of U
#pragma unroll
    for (int l = 0; l < 3; ++l) {
#pragma unroll
      for (int q = 0; q < 4; ++q) {
        const float cq = cp[l * 4 + q], sq = sp[l * 4 + q];
        const int m = 8 >> q;
#pragma unroll
        for (int idx = 0; idx < 16; ++idx) {
          if (idx & m) continue;
          float v0 = st[idx], v1 = st[idx | m];
          st[idx] = cq * v0 - sq * v1;
          st[idx | m] = sq * v0 + cq * v1;
        }
      }
#pragma unroll
      for (int q = 0; q < 3; ++q) {
        const int mc = 8 >> q, mt = 4 >> q;
#pragma unroll
        for (int idx = 0; idx < 16; ++idx) {
          if ((idx & mc) && !(idx & mt)) {
            float t0 = st[idx];
            st[idx] = st[idx | mt];
            st[idx | mt] = t0;
          }
        }
      }
    }
#pragma unroll
    for (int i = 0; i < 16; ++i) U[i * 16 + tid] = st[i];
  }
  for (int t = tid; t < 10 * NP; t += 256) {
    int k = t / NP, p = t - k * NP;
    float s = 0.f;
#pragma unroll
    for (int c = 0; c < 4; ++c) s += res_w[c] * cls_w[k * 784 + c * NP + p];
    W2[t] = s;
  }
}

// ---------------------------------------------------------------------------
// K1: per-patch-position min/max over the batch. Two independent accumulator
// pairs break the fmin/fmax dependency chain; imgs=32 keeps atomic traffic low.
// ---------------------------------------------------------------------------
__global__ void __launch_bounds__(512) minmax_kernel(
    const float* __restrict__ x, unsigned* __restrict__ mn,
    unsigned* __restrict__ mx, int imgs, int B) {
  __shared__ unsigned skmin[392], skmax[392];
  const int t = threadIdx.x;
  const int img0 = blockIdx.x * imgs;
  if (t < 392) {
    const int r = t / 14, j = t - r * 14;
    const float* base = x + (size_t)img0 * 784 + r * 28 + 2 * j;
    const int nimg = (img0 + imgs <= B) ? imgs : (B - img0);
    float lmn0 = 3.4e38f, lmn1 = 3.4e38f;
    float lmx0 = -3.4e38f, lmx1 = -3.4e38f;
    int m = 0;
#pragma unroll 4
    for (; m + 1 < nimg; m += 2) {
      float2 v0 = *(const float2*)(base + (size_t)m * 784);
      float2 v1 = *(const float2*)(base + (size_t)(m + 1) * 784);
      lmn0 = fminf(lmn0, fminf(v0.x, v0.y));
      lmx0 = fmaxf(lmx0, fmaxf(v0.x, v0.y));
      lmn1 = fminf(lmn1, fminf(v1.x, v1.y));
      lmx1 = fmaxf(lmx1, fmaxf(v1.x, v1.y));
    }
    if (m < nimg) {
      float2 v0 = *(const float2*)(base + (size_t)m * 784);
      lmn0 = fminf(lmn0, fminf(v0.x, v0.y));
      lmx0 = fmaxf(lmx0, fmaxf(v0.x, v0.y));
    }
    skmin[t] = fkey(fminf(lmn0, lmn1));
    skmax[t] = fkey(fmaxf(lmx0, lmx1));
  }
  __syncthreads();
  if (t < NP) {
    const int i = t / 14, j = t - i * 14;
    const int f0 = (2 * i) * 14 + j, f1 = f0 + 14;
    unsigned kmn = skmin[f0] < skmin[f1] ? skmin[f0] : skmin[f1];
    unsigned kmx = skmax[f0] > skmax[f1] ? skmax[f0] : skmax[f1];
    atomicMin(&mn[t], kmn);
    atomicMax(&mx[t], kmx);
  }
}

// ---------------------------------------------------------------------------
// K2 (fused circuit + classifier, TWO images per wave): block = 4 waves = 8
// images. Wave iterates q = it*64+lane over [0,392): img = q>=196, p = q%196.
// 7 iterations for 2 images (3.5/image vs 4/image) cuts the dead-lane tail
// from 23% to 12.5%. Dual accumulators; butterfly __shfl_xor reduce leaves
// the sums in ALL lanes, softmax runs SIMT-parallel, and lanes 0..9 emit one
// coalesced 40B store per image (no serial lane-0 epilogue).
// sin/cos in revolutions: 0.25*(v-mn)/(range+1e-8) in [0,0.25], no range
// reduction needed (exact algebra vs reference).
// ---------------------------------------------------------------------------
__global__ void __launch_bounds__(256) fused_kernel(
    const float* __restrict__ x, const unsigned* __restrict__ mnk,
    const unsigned* __restrict__ mxk, const float* __restrict__ U,
    const float* __restrict__ W2, const float* __restrict__ cls_w,
    const float* __restrict__ cls_b, float* __restrict__ out, int B) {
  const int lane = threadIdx.x & 63;
  const int wv = threadIdx.x >> 6;
  const int b0 = blockIdx.x * 8 + wv * 2;
  if (b0 >= B) return;  // wave-uniform
  const bool has1 = (b0 + 1) < B;
  const float* x0 = x + (size_t)b0 * 784;

  float acc0[10], acc1[10];
#pragma unroll
  for (int k = 0; k < 10; ++k) { acc0[k] = 0.f; acc1[k] = 0.f; }

#pragma unroll 1
  for (int it = 0; it < 7; ++it) {
    const int q = it * 64 + lane;
    const int img = (q >= NP) ? 1 : 0;
    const int p = q - (img ? NP : 0);
    const bool valid = (q < 2 * NP) && (!img || has1);
    if (valid) {
      const float* ximg = x0 + (img ? 784 : 0);
      const int i = p / 14, j = p - i * 14;
      const float* px = ximg + (2 * i) * 28 + 2 * j;
      const float2 r0 = *(const float2*)px;
      const float2 r1 = *(const float2*)(px + 28);

      const float mnv = funkey(mnk[p]);
      const float mxv = funkey(mxk[p]);
      // half-angle in revolutions: 0.25*(v-mn)/(range+1e-8) in [0,0.25]
      const float sc = 0.25f / (mxv - mnv + 1e-8f);

      float cc[4], ss[4];
      {
        const float a0 = (r0.x - mnv) * sc;
        const float a1 = (r0.y - mnv) * sc;
        const float a2 = (r1.x - mnv) * sc;
        const float a3 = (r1.y - mnv) * sc;
        ss[0] = __builtin_amdgcn_sinf(a0); cc[0] = __builtin_amdgcn_cosf(a0);
        ss[1] = __builtin_amdgcn_sinf(a1); cc[1] = __builtin_amdgcn_cosf(a1);
        ss[2] = __builtin_amdgcn_sinf(a2); cc[2] = __builtin_amdgcn_cosf(a2);
        ss[3] = __builtin_amdgcn_sinf(a3); cc[3] = __builtin_amdgcn_cosf(a3);
      }

      // product state; index bit (8>>q) = wire q
      float st0[16];
      {
        const float A[4] = {cc[0] * cc[1], cc[0] * ss[1], ss[0] * cc[1], ss[0] * ss[1]};
        const float Bq[4] = {cc[2] * cc[3], cc[2] * ss[3], ss[2] * cc[3], ss[2] * ss[3]};
#pragma unroll
        for (int idx = 0; idx < 16; ++idx) st0[idx] = A[idx >> 2] * Bq[idx & 3];
      }

      // matvec fused with first Walsh stage (pairs) -> a8[8], z3
      float a8[8], z3 = 0.f;
#pragma unroll
      for (int k = 0; k < 8; ++k) {
        float f0 = 0.f, f1 = 0.f;
#pragma unroll
        for (int jx = 0; jx < 16; ++jx) {
          f0 = fmaf(U[(2 * k) * 16 + jx], st0[jx], f0);
          f1 = fmaf(U[(2 * k + 1) * 16 + jx], st0[jx], f1);
        }
        const float s0 = f0 * f0, s1 = f1 * f1;
        a8[k] = s0 + s1;
        z3 += s0 - s1;
      }
      float bb[4], z2 = 0.f;
#pragma unroll
      for (int k = 0; k < 4; ++k) {
        bb[k] = a8[2 * k] + a8[2 * k + 1];
        z2 += a8[2 * k] - a8[2 * k + 1];
      }
      const float e0 = bb[0] + bb[1], e1 = bb[2] + bb[3];
      const float z1 = (bb[0] - bb[1]) + (bb[2] - bb[3]);
      const float z0 = e0 - e1;
      const float v = r0.x;  // residual pixel img[2i,2j]

      // classifier: meas flat f = 4p+w -> cls_w[k*784+4p+w] is one float4
      float tt[10];
#pragma unroll
      for (int k = 0; k < 10; ++k) {
        const float4 w4 = *(const float4*)(cls_w + k * 784 + 4 * p);
        float a = z0 * w4.x;
        a = fmaf(z1, w4.y, a);
        a = fmaf(z2, w4.z, a);
        a = fmaf(z3, w4.w, a);
        tt[k] = fmaf(v, W2[k * NP + p], a);
      }
      if (!img) {
#pragma unroll
        for (int k = 0; k < 10; ++k) acc0[k] += tt[k];
      } else {
#pragma unroll
        for (int k = 0; k < 10; ++k) acc1[k] += tt[k];
      }
    }
  }

  // butterfly reduce: result lands in ALL lanes
#pragma unroll
  for (int k = 0; k < 10; ++k) {
    float a = acc0[k];
#pragma unroll
    for (int off = 32; off > 0; off >>= 1) a += __shfl_xor(a, off, 64);
    acc0[k] = a;
    float c = acc1[k];
#pragma unroll
    for (int off = 32; off > 0; off >>= 1) c += __shfl_xor(c, off, 64);
    acc1[k] = c;
  }

  // SIMT-parallel softmax epilogue (every lane computes; lanes 0..9 store)
  float lg0[10], lg1[10];
#pragma unroll
  for (int k = 0; k < 10; ++k) {
    lg0[k] = acc0[k] + cls_b[k];
    lg1[k] = acc1[k] + cls_b[k];
  }
  float m0 = lg0[0], m1 = lg1[0];
#pragma unroll
  for (int k = 1; k < 10; ++k) { m0 = fmaxf(m0, lg0[k]); m1 = fmaxf(m1, lg1[k]); }
  float s0 = 0.f, s1 = 0.f;
#pragma unroll
  for (int k = 0; k < 10; ++k) { s0 += __expf(lg0[k] - m0); s1 += __expf(lg1[k] - m1); }
  const float lse0 = m0 + __logf(s0);
  const float lse1 = m1 + __logf(s1);

  if (lane < 10) {
    float v0 = lg0[0], v1 = lg1[0];
#pragma unroll
    for (int k = 1; k < 10; ++k) {
      v0 = (lane == k) ? lg0[k] : v0;
      v1 = (lane == k) ? lg1[k] : v1;
    }
    out[(size_t)b0 * 10 + lane] = v0 - lse0;
    if (has1) out[(size_t)(b0 + 1) * 10 + lane] = v1 - lse1;
  }
}

extern "C" void kernel_launch(void* const* d_in, const int* in_sizes, int n_in,
                              void* d_out, int out_size, void* d_ws, size_t ws_size,
                              hipStream_t stream) {
  const float* x      = (const float*)d_in[0];
  const float* params = (const float*)d_in[1];
  const float* res_w  = (const float*)d_in[2];
  const float* cls_w  = (const float*)d_in[3];
  const float* cls_b  = (const float*)d_in[4];
  float* out = (float*)d_out;
  const int B = in_sizes[0] / 784;

  // ws layout: mn[196] u32 | mx[196] u32 | U[256] f32 | W2[1960] f32
  unsigned* mn = (unsigned*)d_ws;
  unsigned* mx = mn + NP;
  float* U  = (float*)(mx + NP);
  float* W2 = U + 256;

  precompute_kernel<<<1, 256, 0, stream>>>(params, res_w, cls_w, U, W2, mn, mx);

  const int imgs = 32;
  const int nblk1 = (B + imgs - 1) / imgs;
  minmax_kernel<<<nblk1, 512, 0, stream>>>(x, mn, mx, imgs, B);

  const int nblk2 = (B + 7) / 8;
  fused_kernel<<<nblk2, 256, 0, stream>>>(x, mn, mx, U, W2, cls_w, cls_b, out, B);
}